// Round 7
// baseline (1194.052 us; speedup 1.0000x reference)
//
#include <hip/hip_runtime.h>

#define T_STEPS 16
#define BATCH 16
#define XHW (100*768)
#define M2_ELEMS (BATCH*32*25*192)    // 2,457,600
#define C4_ELEMS (BATCH*25*192)       // 76,800
#define H3_ELEMS (BATCH*64*25*192)    // 4,915,200

// ===================== persistent fused scan kernel ==========================
// Block = (b, rg 0..12, wseg 0..5). Owns mem2 rows 2rg..2rg+1, cols c0..c0+31.
// mem1 state in registers (rows m=4rg-1..4rg+3, cols gc=2c0-1..2c0+64; halo
// rows/cols recomputed identically by neighbor blocks -> deterministic).
// Spikes live one step in LDS (f32, bank-conflict-free geometry).
// x is read directly from global (L1-hot tile, 16-lane broadcast dedup).
__global__ __launch_bounds__(256) void k_scan(
    const float* __restrict__ x_seq, // [T,B,100,768]
    const float* __restrict__ w1,    // [16,1,5,5]
    const float* __restrict__ b1,    // [16]
    const float* __restrict__ w2,    // [32,16,3,3]
    const float* __restrict__ b2,    // [32]
    float* __restrict__ mem2)        // [B,32,25,192] final state out
{
    __shared__ float s1s[5][16][76];  // spike tile; 76 = 4-mult pad, ch-stride 2-way
    __shared__ float w2s[32 * 196];   // [oc][ic*12+k], 196-pad -> oc*196%32 distinct

    const int tid  = threadIdx.x;
    const int bxx  = blockIdx.x;      // wseg*13 + rg
    const int b    = blockIdx.y;
    const int wseg = bxx / 13;
    const int rg   = bxx % 13;
    const int c0   = wseg * 32;

    // ---- one-time staging: transposed w2 + zeroed spikes ----
    for (int idx = tid; idx < 6144; idx += 256) {
        int o = idx / 192, r = idx % 192;
        int icc = r / 12, kk = r % 12;
        w2s[o * 196 + icc * 12 + kk] = (kk < 9) ? w2[o * 144 + icc * 9 + kk] : 0.f;
    }
    for (int i = tid; i < 5 * 16 * 76; i += 256) ((float*)s1s)[i] = 0.f;

    // ---- conv1 statics: 16 lanes (ch) broadcast per item; ig = item group ----
    const int ch = tid & 15;
    const int ig = tid >> 4;
    float w1reg[25];
#pragma unroll
    for (int k = 0; k < 25; k++) w1reg[k] = w1[ch * 25 + k];
    const float b1reg = b1[ch];

    int it_i[3], it_cn[3];
    bool it_ok[3];
#pragma unroll
    for (int k = 0; k < 3; k++) {
        int item = ig + 16 * k;
        int i = item / 9, cn = item % 9;
        int m = 4 * rg - 1 + i;
        it_i[k] = i; it_cn[k] = cn;
        it_ok[k] = (item < 45) && (m >= 0) && (m <= 49);
    }

    // ---- conv2 statics: thread = (oc, cg); 4 cols x 2 rows ----
    const int oc = tid >> 3;          // 0..31
    const int cg = tid & 7;           // 0..7
    const float bb = b2[oc];
    const float* wrow = &w2s[oc * 196];

    float m1reg[3][8];
#pragma unroll
    for (int k = 0; k < 3; k++)
#pragma unroll
        for (int c = 0; c < 8; c++) m1reg[k][c] = 0.f;
    float m2r[2][4];
#pragma unroll
    for (int r = 0; r < 2; r++)
#pragma unroll
        for (int c = 0; c < 4; c++) m2r[r][c] = 0.f;

    __syncthreads();

    const float4 z4 = make_float4(0.f, 0.f, 0.f, 0.f);

    for (int t = 0; t < T_STEPS; t++) {
        const float* xb = x_seq + ((size_t)t * BATCH + b) * XHW;

        // ---- conv1 + LIF1: 3 items/thread, x from global, spikes -> LDS ----
#pragma unroll
        for (int k = 0; k < 3; k++) {
            if (!it_ok[k]) continue;
            int i = it_i[k], cn = it_cn[k];
            int lcb = 8 * cn;
            int xcb = 4 * c0 + 16 * cn - 4;       // x col base
            float acc[8];
#pragma unroll
            for (int c = 0; c < 8; c++) acc[c] = b1reg;
#pragma unroll
            for (int kh = 0; kh < 5; kh++) {
                int xr = 8 * rg - 4 + 2 * i + kh; // x row
                bool rok = (unsigned)xr < 100u;
                const float* xp = &xb[xr * 768];
                float4 v[5];
#pragma unroll
                for (int j = 0; j < 5; j++) {
                    int colj = xcb + 4 * j;
                    bool ok = rok && (colj >= 0) && (colj <= 764);
                    v[j] = ok ? *(const float4*)&xp[colj] : z4;
                }
                float xv[20] = {v[0].x, v[0].y, v[0].z, v[0].w,
                                v[1].x, v[1].y, v[1].z, v[1].w,
                                v[2].x, v[2].y, v[2].z, v[2].w,
                                v[3].x, v[3].y, v[3].z, v[3].w,
                                v[4].x, v[4].y, v[4].z, v[4].w};
#pragma unroll
                for (int kw = 0; kw < 5; kw++) {
                    float w = w1reg[kh * 5 + kw];
#pragma unroll
                    for (int c = 0; c < 8; c++)
                        acc[c] = fmaf(xv[2 * c + kw], w, acc[c]);
                }
            }
            float out[8];
#pragma unroll
            for (int c = 0; c < 8; c++) {
                int lc = lcb + c;
                int gc = 2 * c0 - 1 + lc;
                bool valid = (lc < 66) && (gc >= 0) && (gc < 384);
                float mn = m1reg[k][c] * 0.5f + acc[c];
                bool f = (mn >= 1.0f);
                out[c] = (f && valid) ? 1.f : 0.f;
                if (valid) m1reg[k][c] = f ? 0.f : mn;
            }
            float* dst = &s1s[i][ch][lcb];
            *(float4*)dst       = make_float4(out[0], out[1], out[2], out[3]);
            *(float4*)(dst + 4) = make_float4(out[4], out[5], out[6], out[7]);
        }
        __syncthreads();   // spikes ready

        // ---- conv2 + LIF2: 4 cols x 2 rows, conflict-free LDS reads ----
        {
            float acc0[4] = {0.f, 0.f, 0.f, 0.f};
            float acc1[4] = {0.f, 0.f, 0.f, 0.f};
#pragma unroll
            for (int ic = 0; ic < 16; ic++) {
                const float* wr = &wrow[ic * 12];
                float4 wa = *(const float4*)wr;
                float4 wb2 = *(const float4*)(wr + 4);
                float wq[9] = {wa.x, wa.y, wa.z, wa.w,
                               wb2.x, wb2.y, wb2.z, wb2.w, wr[8]};
#pragma unroll
                for (int i = 0; i < 5; i++) {
                    const float* sp = &s1s[i][ic][8 * cg];
                    float4 a = *(const float4*)sp;
                    float4 d = *(const float4*)(sp + 4);
                    float4 e = *(const float4*)(sp + 8);
                    float sv[12] = {a.x, a.y, a.z, a.w,
                                    d.x, d.y, d.z, d.w,
                                    e.x, e.y, e.z, e.w};
                    if (i < 3) {             // row for out-row0, kh = i
                        float k0 = wq[i * 3], k1 = wq[i * 3 + 1], k2 = wq[i * 3 + 2];
#pragma unroll
                        for (int c = 0; c < 4; c++)
                            acc0[c] += fmaf(sv[2 * c], k0,
                                       fmaf(sv[2 * c + 1], k1, sv[2 * c + 2] * k2));
                    }
                    if (i >= 2) {            // row for out-row1, kh = i-2
                        int kk = (i - 2) * 3;
                        float k0 = wq[kk], k1 = wq[kk + 1], k2 = wq[kk + 2];
#pragma unroll
                        for (int c = 0; c < 4; c++)
                            acc1[c] += fmaf(sv[2 * c], k0,
                                       fmaf(sv[2 * c + 1], k1, sv[2 * c + 2] * k2));
                    }
                }
            }
#pragma unroll
            for (int c = 0; c < 4; c++) {
                float mn0 = m2r[0][c] * 0.5f + (acc0[c] + bb);
                m2r[0][c] = (mn0 >= 1.0f) ? 0.f : mn0;
                float mn1 = m2r[1][c] * 0.5f + (acc1[c] + bb);
                m2r[1][c] = (mn1 >= 1.0f) ? 0.f : mn1;
            }
        }
        __syncthreads();   // conv2 done with s1s before next-step overwrite
    }

    // ---- write final mem2 ----
    {
        int cb = c0 + 4 * cg;
        int base = ((b * 32 + oc) * 25 + 2 * rg) * 192 + cb;
        *(float4*)&mem2[base] = make_float4(m2r[0][0], m2r[0][1], m2r[0][2], m2r[0][3]);
        if (2 * rg + 1 < 25)
            *(float4*)&mem2[base + 192] =
                make_float4(m2r[1][0], m2r[1][1], m2r[1][2], m2r[1][3]);
    }
}

// ========== K3: conv3 + bias + relu (2 output rows/thread, float4 w) =========
__global__ __launch_bounds__(192) void k3_conv3_relu(
    const float* __restrict__ mem2,  // [B,32,25,192]
    const float* __restrict__ w3,    // [64,32,3,3]
    const float* __restrict__ b3,    // [64]
    float* __restrict__ h)           // [B,64,25,192]
{
    __shared__ float wsm[288 * 16];  // [r=ic*9+kk][oc_local 16]
    __shared__ float bsm[16];
    int ocbase = blockIdx.y * 16;
    for (int i = threadIdx.x; i < 4608; i += 192) {
        int o = i & 15, rr = i >> 4;
        wsm[i] = w3[(ocbase + o) * 288 + rr];
    }
    if (threadIdx.x < 16) bsm[threadIdx.x] = b3[ocbase + threadIdx.x];
    __syncthreads();

    int j   = threadIdx.x;           // col 0..191
    int bx  = blockIdx.x;            // b*13 + ohp
    int b   = bx / 13, ohp = bx % 13;
    int oh0 = ohp * 2;
    bool r1ok = (oh0 + 1) < 25;

    float acc0[16], acc1[16];
#pragma unroll
    for (int o = 0; o < 16; o++) { acc0[o] = bsm[o]; acc1[o] = bsm[o]; }

    const float* mb = mem2 + b * (32 * 25 * 192);
    for (int ic = 0; ic < 32; ic++) {
        const float* mc = mb + ic * (25 * 192);
        float rw[4][3];
#pragma unroll
        for (int q = 0; q < 4; q++) {
            int ih = oh0 - 1 + q;
            bool okh = (unsigned)ih < 25u;
#pragma unroll
            for (int c = 0; c < 3; c++) {
                int iw = j - 1 + c;
                rw[q][c] = (okh && (unsigned)iw < 192u) ? mc[ih * 192 + iw] : 0.f;
            }
        }
#pragma unroll
        for (int kh = 0; kh < 3; kh++) {
#pragma unroll
            for (int kw = 0; kw < 3; kw++) {
                const float4* wp = (const float4*)&wsm[((ic * 3 + kh) * 3 + kw) * 16];
                float v0 = rw[kh][kw], v1 = rw[kh + 1][kw];
#pragma unroll
                for (int g = 0; g < 4; g++) {
                    float4 wv = wp[g];
                    acc0[g*4+0] = fmaf(v0, wv.x, acc0[g*4+0]);
                    acc0[g*4+1] = fmaf(v0, wv.y, acc0[g*4+1]);
                    acc0[g*4+2] = fmaf(v0, wv.z, acc0[g*4+2]);
                    acc0[g*4+3] = fmaf(v0, wv.w, acc0[g*4+3]);
                    acc1[g*4+0] = fmaf(v1, wv.x, acc1[g*4+0]);
                    acc1[g*4+1] = fmaf(v1, wv.y, acc1[g*4+1]);
                    acc1[g*4+2] = fmaf(v1, wv.z, acc1[g*4+2]);
                    acc1[g*4+3] = fmaf(v1, wv.w, acc1[g*4+3]);
                }
            }
        }
    }
#pragma unroll
    for (int o = 0; o < 16; o++) {
        int idx = ((b * 64 + ocbase + o) * 25 + oh0) * 192 + j;
        h[idx] = fmaxf(acc0[o], 0.f);
        if (r1ok) h[idx + 192] = fmaxf(acc1[o], 0.f);
    }
}

// ========== K4: conv4 partials (16-ic slice per blockIdx.y, atomicAdd) =======
__global__ __launch_bounds__(256) void k4_conv4(
    const float* __restrict__ h,    // [B,64,25,192]
    const float* __restrict__ w4,   // [1,64,3,3]
    float* __restrict__ c4)         // [B,25,192] (pre-zeroed; bias in k5)
{
    __shared__ float wsm[144];
    int icbase = blockIdx.y * 16;
    for (int i = threadIdx.x; i < 144; i += 256) wsm[i] = w4[icbase * 9 + i];
    __syncthreads();

    int gid = blockIdx.x * 256 + threadIdx.x;
    int ow = gid % 192;
    int t2 = gid / 192;
    int oh = t2 % 25;
    int b  = t2 / 25;

    float acc = 0.f;
    const float* hb = h + (b * 64 + icbase) * (25 * 192);
    for (int ic = 0; ic < 16; ic++) {
        const float* hc = hb + ic * (25 * 192);
#pragma unroll
        for (int kh = 0; kh < 3; kh++) {
            int ih = oh - 1 + kh;
            bool okh = (unsigned)ih < 25u;
#pragma unroll
            for (int kw = 0; kw < 3; kw++) {
                int iw = ow - 1 + kw;
                float v = (okh && (unsigned)iw < 192u) ? hc[ih * 192 + iw] : 0.f;
                acc = fmaf(v, wsm[ic * 9 + kh * 3 + kw], acc);
            }
        }
    }
    atomicAdd(&c4[gid], acc);
}

// ========== K5: + bias, bilinear x4 (align_corners=False), softplus ==========
__global__ __launch_bounds__(256) void k5_resize_softplus(
    const float* __restrict__ c4,   // [B,25,192]
    const float* __restrict__ b4,   // [1]
    float* __restrict__ out)        // [B,100,768]
{
    int gid = blockIdx.x * 256 + threadIdx.x;
    int ox = gid % 768;
    int t2 = gid / 768;
    int oy = t2 % 100;
    int b  = t2 / 100;

    float bias = b4[0];
    float sy = (oy + 0.5f) * 0.25f - 0.5f;
    float sx = (ox + 0.5f) * 0.25f - 0.5f;
    int y0 = (int)floorf(sy); float fy = sy - (float)y0;
    int x0 = (int)floorf(sx); float fx = sx - (float)x0;
    int y1 = y0 + 1, x1 = x0 + 1;
    y0 = y0 < 0 ? 0 : (y0 > 24 ? 24 : y0);
    y1 = y1 < 0 ? 0 : (y1 > 24 ? 24 : y1);
    x0 = x0 < 0 ? 0 : (x0 > 191 ? 191 : x0);
    x1 = x1 < 0 ? 0 : (x1 > 191 ? 191 : x1);

    const float* cb = c4 + b * 4800;
    float v00 = cb[y0 * 192 + x0] + bias, v01 = cb[y0 * 192 + x1] + bias;
    float v10 = cb[y1 * 192 + x0] + bias, v11 = cb[y1 * 192 + x1] + bias;
    float v = (1.f - fy) * ((1.f - fx) * v00 + fx * v01)
            +        fy  * ((1.f - fx) * v10 + fx * v11);
    out[gid] = fmaxf(v, 0.f) + log1pf(expf(-fabsf(v)));
}

extern "C" void kernel_launch(void* const* d_in, const int* in_sizes, int n_in,
                              void* d_out, int out_size, void* d_ws, size_t ws_size,
                              hipStream_t stream) {
    const float* x_seq = (const float*)d_in[0];
    const float* w1 = (const float*)d_in[1];
    const float* b1 = (const float*)d_in[2];
    const float* w2 = (const float*)d_in[3];
    const float* b2 = (const float*)d_in[4];
    const float* w3 = (const float*)d_in[5];
    const float* b3 = (const float*)d_in[6];
    const float* w4 = (const float*)d_in[7];
    const float* b4 = (const float*)d_in[8];
    float* out = (float*)d_out;

    // ws layout (floats): [mem2 M2][c4 C4][h H3]
    float* ws   = (float*)d_ws;
    float* mem2 = ws;
    float* c4o  = ws + M2_ELEMS;
    float* h    = ws + M2_ELEMS + C4_ELEMS;

    // only c4 needs zeroing (atomic accumulation target)
    hipMemsetAsync(c4o, 0, (size_t)C4_ELEMS * sizeof(float), stream);

    k_scan<<<dim3(78, 16), 256, 0, stream>>>(x_seq, w1, b1, w2, b2, mem2);
    k3_conv3_relu<<<dim3(16 * 13, 4), 192, 0, stream>>>(mem2, w3, b3, h);
    k4_conv4<<<dim3(300, 4), 256, 0, stream>>>(h, w4, c4o);
    k5_resize_softplus<<<4800, 256, 0, stream>>>(c4o, b4, out);
}